// Round 15
// baseline (786.599 us; speedup 1.0000x reference)
//
#include <hip/hip_runtime.h>
#include <math.h>

#define BFULL 8
#define HH 64
#define WWI 64
#define CC 256
#define NN 16384
#define INDIM 810
#define XP 832          // X padded cols (zero-filled 810..831)
#define K3P 1088        // concat layer K padded (256 + 832)
#define MLPW 256
#define FBM 128         // fused-MLP rows per block
#define HSTR 260        // H LDS row stride (u16): 130 dwords -> uniform 8/bank reads, 2-way (free) epi writes

typedef unsigned short u16;
typedef __attribute__((ext_vector_type(8))) short short8;
typedef __attribute__((ext_vector_type(4))) float f32x4;

__device__ __forceinline__ u16 f2bf(float f){
  union{float f; unsigned u;} v; v.f=f;
  unsigned r = v.u + 0x7FFFu + ((v.u>>16)&1u);   // RNE
  return (u16)(r>>16);
}
__device__ __forceinline__ float bf2f(u16 h){
  union{unsigned u; float f;} v; v.u = ((unsigned)h)<<16; return v.f;
}
// tanh-approx gelu; 1-2/(e^{2z}+1) saturates cleanly (no NaN at inf/0)
__device__ __forceinline__ float gelu_fast(float x){
  float z = 0.7978845608028654f*(x + 0.044715f*x*x*x);
  float e = __expf(2.0f*z);
  float t = 1.0f - 2.0f/(e + 1.0f);
  return 0.5f*x*(1.0f+t);
}

// ---------------- pyramid resize (jax.image.resize bilinear, antialias=True) ----------------
template<int OUTD, int RR>
__global__ __launch_bounds__(256) void resize_kernel(const float* __restrict__ in,
                                                     float* __restrict__ out){
  int bidx = blockIdx.x;
  int ox = bidx % OUTD;
  int oy = (bidx / OUTD) % OUTD;
  int b  = bidx / (OUTD*OUTD);
  int c = threadIdx.x;

  float sy = (oy + 0.5f)*RR - 0.5f;
  float sx = (ox + 0.5f)*RR - 0.5f;
  int jy0 = (int)floorf(sy) - RR + 1;
  int jx0 = (int)floorf(sx) - RR + 1;

  float wy[2*RR], wx[2*RR];
  int   jys[2*RR], jxs[2*RR];
  int cy=0, cx=0; float sumy=0.f, sumx=0.f;
  #pragma unroll
  for(int t=0;t<2*RR;t++){
    int j = jy0 + t;
    if(j>=0 && j<HH){
      float w = 1.0f - fabsf((float)j - sy)/(float)RR;
      if(w > 0.f){ jys[cy]=j; wy[cy]=w; sumy+=w; cy++; }
    }
  }
  #pragma unroll
  for(int t=0;t<2*RR;t++){
    int j = jx0 + t;
    if(j>=0 && j<WWI){
      float w = 1.0f - fabsf((float)j - sx)/(float)RR;
      if(w > 0.f){ jxs[cx]=j; wx[cx]=w; sumx+=w; cx++; }
    }
  }
  float acc = 0.f;
  for(int i=0;i<cy;i++)
    for(int j=0;j<cx;j++)
      acc += wy[i]*wx[j]*in[(((size_t)b*HH + jys[i])*WWI + jxs[j])*CC + c];
  acc /= (sumy*sumx);
  out[(((size_t)b*OUTD + oy)*OUTD + ox)*CC + c] = acc;
}

// ------------- posenc + pyramid sampling -> X rows [chunk][XP] bf16, vectorized -------------
__global__ __launch_bounds__(256) void sample_encode_v2(
    const float* __restrict__ fg, const float* __restrict__ pyr1,
    const float* __restrict__ pyr2, const float* __restrict__ coords,
    u16* __restrict__ X, int m0, int mcount){
  int mi = blockIdx.x*2 + (threadIdx.x >> 7);
  if(mi >= mcount) return;
  int u = threadIdx.x & 127;
  int m = m0 + mi;
  int b = m / NN;
  int n = m % NN;
  float c0 = coords[(size_t)n*2 + 0];
  float c1 = coords[(size_t)n*2 + 1];
  u16* xrow = X + (size_t)mi*XP;

  if(u >= 64){
    if(u < 106){
      int p = u - 64;
      float v;
      if(p < 2){ v = (p==0) ? c0 : c1; }
      else {
        int k = (p-2) >> 2;
        int r = (p-2) & 3;
        float f = (float)(1u<<k) * 3.14159265358979323846f;
        float a = (r & 1) ? c1 : c0;
        v = (r < 2) ? sinf(a*f) : cosf(a*f);
      }
      xrow[p] = f2bf(v);
    } else {
      xrow[INDIM + (u - 106)] = 0;       // pad 810..831 (22 cols)
    }
    return;
  }

  int c4 = u*4;
  const float* grids[3];
  grids[0] = fg   + (size_t)b*HH*WWI*CC;
  grids[1] = pyr1 + (size_t)b*32*32*CC;
  grids[2] = pyr2 + (size_t)b*16*16*CC;
  const int dims[3] = {64, 32, 16};

  #pragma unroll
  for(int lvl=0; lvl<3; lvl++){
    int d = dims[lvl];
    float yy = (c0 + 1.0f)*0.5f*(float)(d-1);
    float xx = (c1 + 1.0f)*0.5f*(float)(d-1);
    yy = fminf(fmaxf(yy, 0.0f), (float)(d-1));
    xx = fminf(fmaxf(xx, 0.0f), (float)(d-1));
    int y0 = (int)yy, x0 = (int)xx;
    int y1 = min(y0+1, d-1), x1 = min(x0+1, d-1);
    float ty = yy - (float)y0, tx = xx - (float)x0;
    const float* g = grids[lvl];
    float4 v00 = *(const float4*)&g[((size_t)y0*d + x0)*CC + c4];
    float4 v01 = *(const float4*)&g[((size_t)y0*d + x1)*CC + c4];
    float4 v10 = *(const float4*)&g[((size_t)y1*d + x0)*CC + c4];
    float4 v11 = *(const float4*)&g[((size_t)y1*d + x1)*CC + c4];
    float w00 = (1.f-ty)*(1.f-tx), w01 = (1.f-ty)*tx, w10 = ty*(1.f-tx), w11 = ty*tx;
    float r0 = w00*v00.x + w01*v01.x + w10*v10.x + w11*v11.x;
    float r1 = w00*v00.y + w01*v01.y + w10*v10.y + w11*v11.y;
    float r2 = w00*v00.z + w01*v01.z + w10*v10.z + w11*v11.z;
    float r3 = w00*v00.w + w01*v01.w + w10*v10.w + w11*v11.w;
    unsigned lo = (unsigned)f2bf(r0) | ((unsigned)f2bf(r1) << 16);
    unsigned hi = (unsigned)f2bf(r2) | ((unsigned)f2bf(r3) << 16);
    unsigned* dst = (unsigned*)&xrow[42 + lvl*CC + c4];
    dst[0] = lo; dst[1] = hi;
  }
}

// ---------------- weight convert: W[k][256] fp32 -> Wb[n][Kp] bf16 (B^T, zero-padded) ------
__global__ __launch_bounds__(256) void wconv(const float* __restrict__ W,
                                             u16* __restrict__ Wb, int K, int Kp){
  int idx = blockIdx.x*256 + threadIdx.x;
  if(idx >= 256*Kp) return;
  int n = idx / Kp, k = idx % Kp;
  float v = (k < K) ? W[(size_t)k*MLPW + n] : 0.f;
  Wb[idx] = f2bf(v);
}

// wo [256][3] fp32 -> wob[16][256] bf16 (B^T, rows 3..15 zero)
__global__ __launch_bounds__(256) void wconv_out(const float* __restrict__ wo,
                                                 u16* __restrict__ wob){
  int idx = blockIdx.x*256 + threadIdx.x;
  if(idx >= 16*256) return;
  int n = idx >> 8, k = idx & 255;
  float v = (n < 3) ? wo[(size_t)k*3 + n] : 0.f;
  wob[idx] = f2bf(v);
}

// ---------------- fused MLP: barrier-free K-loops; A from global X or LDS H ----------------
__global__ __launch_bounds__(512, 4) void fused_mlp(
    const u16* __restrict__ X,
    const u16* __restrict__ wb0, const u16* __restrict__ wb1,
    const u16* __restrict__ wb2, const u16* __restrict__ wb3,
    const u16* __restrict__ wob,
    const float* __restrict__ b0, const float* __restrict__ b1,
    const float* __restrict__ b2, const float* __restrict__ b3,
    const float* __restrict__ bo,
    float* __restrict__ out, int m0){
  __shared__ u16 Hs[FBM*HSTR];     // 66560 B
  __shared__ float Os[FBM*4];      // 2048 B  (68608 total -> 2 blocks/CU)

  int tid  = threadIdx.x;
  int lane = tid & 63, wv = tid >> 6;
  int wr = (wv>>2)*64, wc = (wv&3)*64;
  int rl = lane & 15;
  int koffe = (lane >> 4)*8;          // k-slice offset within a 32-K fragment
  int rg = (lane >> 4)*4;             // C/D row group

  size_t gm = (size_t)blockIdx.x*FBM;

  f32x4 acc[4][4];
  #pragma unroll
  for(int i=0;i<4;i++)
    #pragma unroll
    for(int j=0;j<4;j++) acc[i][j] = (f32x4){0.f,0.f,0.f,0.f};

  // per-lane global base for A-fragments from X (rows wr+f*16+rl)
  const u16* xA = X + (gm + wr + rl)*XP + koffe;

  auto loadB = [&](const u16* bw, int Kp2, int gk, short8 bf[4]){
    #pragma unroll
    for(int f=0; f<4; f++)
      bf[f] = *(const short8*)&bw[(size_t)(wc + f*16 + rl)*Kp2 + gk + koffe];
  };
  auto domfma = [&](short8 af[4], short8 bf[4]){
    #pragma unroll
    for(int i=0;i<4;i++)
      #pragma unroll
      for(int j=0;j<4;j++)
        acc[i][j] = __builtin_amdgcn_mfma_f32_16x16x32_bf16(af[i], bf[j], acc[i][j], 0,0,0);
  };
  auto epilogue = [&](const float* __restrict__ bias){
    __syncthreads();                       // all reads of Hs finished
    #pragma unroll
    for(int j=0;j<4;j++){
      int ncol = wc + j*16 + rl;
      float bv = bias[ncol];
      #pragma unroll
      for(int i=0;i<4;i++)
        #pragma unroll
        for(int r=0;r<4;r++){
          int row = wr + i*16 + rg + r;
          Hs[row*HSTR + ncol] = f2bf(gelu_fast(acc[i][j][r] + bv));
        }
    }
    __syncthreads();
    #pragma unroll
    for(int i=0;i<4;i++)
      #pragma unroll
      for(int j=0;j<4;j++) acc[i][j] = (f32x4){0.f,0.f,0.f,0.f};
  };

  // ---- layer 0: X(832) @ w0, A direct from global (no barriers) ----
  #pragma unroll 2
  for(int kc=0; kc<26; kc++){
    short8 af[4], bf[4];
    #pragma unroll
    for(int f=0; f<4; f++)
      af[f] = *(const short8*)(xA + (size_t)(f*16)*XP + kc*32);
    loadB(wb0, XP, kc*32, bf);
    domfma(af, bf);
  }
  epilogue(b0);

  // ---- layers 1,2: H(256) @ w, A from LDS (no barriers inside) ----
  #pragma unroll
  for(int kc=0; kc<8; kc++){
    short8 af[4], bf[4];
    loadB(wb1, 256, kc*32, bf);
    #pragma unroll
    for(int f=0; f<4; f++)
      af[f] = *(const short8*)&Hs[(wr + f*16 + rl)*HSTR + kc*32 + koffe];
    domfma(af, bf);
  }
  epilogue(b1);
  #pragma unroll
  for(int kc=0; kc<8; kc++){
    short8 af[4], bf[4];
    loadB(wb2, 256, kc*32, bf);
    #pragma unroll
    for(int f=0; f<4; f++)
      af[f] = *(const short8*)&Hs[(wr + f*16 + rl)*HSTR + kc*32 + koffe];
    domfma(af, bf);
  }
  epilogue(b2);

  // ---- layer 3: concat(H,X)(1088) @ w3 ----
  #pragma unroll
  for(int kc=0; kc<8; kc++){
    short8 af[4], bf[4];
    loadB(wb3, K3P, kc*32, bf);
    #pragma unroll
    for(int f=0; f<4; f++)
      af[f] = *(const short8*)&Hs[(wr + f*16 + rl)*HSTR + kc*32 + koffe];
    domfma(af, bf);
  }
  #pragma unroll 2
  for(int kc=0; kc<26; kc++){
    short8 af[4], bf[4];
    #pragma unroll
    for(int f=0; f<4; f++)
      af[f] = *(const short8*)(xA + (size_t)(f*16)*XP + kc*32);
    loadB(wb3, K3P, 256 + kc*32, bf);
    domfma(af, bf);
  }
  epilogue(b3);

  // ---- output layer via MFMA (waves 0,1), coalesced store via Os ----
  if(wv < 2){
    f32x4 oa[4];
    #pragma unroll
    for(int i=0;i<4;i++) oa[i] = (f32x4){0.f,0.f,0.f,0.f};
    #pragma unroll
    for(int c=0;c<8;c++){
      short8 af[4];
      #pragma unroll
      for(int f=0; f<4; f++)
        af[f] = *(const short8*)&Hs[(wv*64 + f*16 + rl)*HSTR + c*32 + koffe];
      short8 bf1 = *(const short8*)&wob[(size_t)rl*256 + c*32 + koffe];
      #pragma unroll
      for(int i=0;i<4;i++)
        oa[i] = __builtin_amdgcn_mfma_f32_16x16x32_bf16(af[i], bf1, oa[i], 0,0,0);
    }
    if(rl < 3){
      #pragma unroll
      for(int i=0;i<4;i++)
        #pragma unroll
        for(int r=0;r<4;r++)
          Os[(wv*64 + i*16 + rg + r)*4 + rl] = oa[i][r];
    }
  }
  __syncthreads();
  if(tid < FBM*3){
    float v = Os[(tid/3)*4 + (tid%3)];
    out[((size_t)m0 + gm)*3 + tid] = tanhf(v + bo[tid%3]);
  }
}

extern "C" void kernel_launch(void* const* d_in, const int* in_sizes, int n_in,
                              void* d_out, int out_size, void* d_ws, size_t ws_size,
                              hipStream_t stream){
  const float* fg     = (const float*)d_in[0];
  const float* coords = (const float*)d_in[1];
  const float* w0 = (const float*)d_in[2];  const float* b0 = (const float*)d_in[3];
  const float* w1 = (const float*)d_in[4];  const float* b1 = (const float*)d_in[5];
  const float* w2 = (const float*)d_in[6];  const float* b2 = (const float*)d_in[7];
  const float* w3 = (const float*)d_in[8];  const float* b3 = (const float*)d_in[9];
  const float* wo = (const float*)d_in[10]; const float* bo = (const float*)d_in[11];
  float* out = (float*)d_out;

  char* ws = (char*)d_ws;
  size_t off = 0;
  auto alloc = [&](size_t bytes)->void*{
    void* p = ws + off;
    off += (bytes + 255) & ~(size_t)255;
    return p;
  };
  auto rnd = [](size_t bytes)->size_t{ return (bytes + 255) & ~(size_t)255; };

  size_t fixed =
      rnd((size_t)BFULL*32*32*CC*4) + rnd((size_t)BFULL*16*16*CC*4) +
      rnd((size_t)256*XP*2) + rnd((size_t)256*256*2) +
      rnd((size_t)256*256*2) + rnd((size_t)256*K3P*2) + rnd((size_t)16*256*2);

  const size_t Mtot = (size_t)BFULL*NN; // 131072
  size_t chunk = Mtot;
  while(chunk > 128){
    size_t need = fixed + rnd(chunk*(size_t)XP*2);
    if(need <= ws_size) break;
    chunk >>= 1;
  }
  size_t min_need = fixed + rnd(chunk*(size_t)XP*2);
  if(min_need > ws_size || (chunk % 128) != 0) return;

  float* pyr1 = (float*)alloc((size_t)BFULL*32*32*CC*4);
  float* pyr2 = (float*)alloc((size_t)BFULL*16*16*CC*4);
  u16* wb0 = (u16*)alloc((size_t)256*XP*2);
  u16* wb1 = (u16*)alloc((size_t)256*256*2);
  u16* wb2 = (u16*)alloc((size_t)256*256*2);
  u16* wb3 = (u16*)alloc((size_t)256*K3P*2);
  u16* wob = (u16*)alloc((size_t)16*256*2);
  u16* X  = (u16*)alloc(chunk*(size_t)XP*2);

  resize_kernel<32,2><<<dim3(BFULL*32*32), dim3(256), 0, stream>>>(fg, pyr1);
  resize_kernel<16,4><<<dim3(BFULL*16*16), dim3(256), 0, stream>>>(fg, pyr2);
  wconv<<<dim3((256*XP +255)/256), dim3(256), 0, stream>>>(w0, wb0, INDIM, XP);
  wconv<<<dim3((256*256 +255)/256), dim3(256), 0, stream>>>(w1, wb1, 256, 256);
  wconv<<<dim3((256*256 +255)/256), dim3(256), 0, stream>>>(w2, wb2, 256, 256);
  wconv<<<dim3((256*K3P +255)/256), dim3(256), 0, stream>>>(w3, wb3, MLPW+INDIM, K3P);
  wconv_out<<<dim3(16), dim3(256), 0, stream>>>(wo, wob);

  for(size_t m0=0; m0<Mtot; m0+=chunk){
    int mc = (int)chunk;
    sample_encode_v2<<<dim3(mc/2), dim3(256), 0, stream>>>(fg, pyr1, pyr2, coords, X, (int)m0, mc);
    fused_mlp<<<dim3(mc/FBM), dim3(512), 0, stream>>>(X, wb0, wb1, wb2, wb3, wob,
                                                      b0, b1, b2, b3, bo,
                                                      out, (int)m0);
  }
}

// Round 16
// 689.044 us; speedup vs baseline: 1.1416x; 1.1416x over previous
//
#include <hip/hip_runtime.h>
#include <math.h>

#define BFULL 8
#define HH 64
#define WWI 64
#define CC 256
#define NN 16384
#define INDIM 810
#define XP 832          // X padded cols (zero-filled 810..831)
#define K3P 1088        // concat layer K padded (256 + 832)
#define MLPW 256
#define FBM 128         // fused-MLP rows per block
#define HSTR 260        // H LDS row stride (u16): uniform-bank reads/writes (verified: 12K conflicts)

typedef unsigned short u16;
typedef __attribute__((ext_vector_type(8))) short short8;
typedef __attribute__((ext_vector_type(4))) float f32x4;

__device__ __forceinline__ u16 f2bf(float f){
  union{float f; unsigned u;} v; v.f=f;
  unsigned r = v.u + 0x7FFFu + ((v.u>>16)&1u);   // RNE
  return (u16)(r>>16);
}
__device__ __forceinline__ float bf2f(u16 h){
  union{unsigned u; float f;} v; v.u = ((unsigned)h)<<16; return v.f;
}
__device__ __forceinline__ float gelu_fast(float x){
  float z = 0.7978845608028654f*(x + 0.044715f*x*x*x);
  float e = __expf(2.0f*z);
  float t = 1.0f - 2.0f/(e + 1.0f);
  return 0.5f*x*(1.0f+t);
}
// async global->LDS, 16B per lane; lds base must be wave-uniform (HW adds lane*16)
__device__ __forceinline__ void gl16(const u16* g, u16* l){
  __builtin_amdgcn_global_load_lds(
      (const __attribute__((address_space(1))) unsigned int*)g,
      (__attribute__((address_space(3))) unsigned int*)l, 16, 0, 0);
}

// ---------------- pyramid resize (jax.image.resize bilinear, antialias=True) ----------------
template<int OUTD, int RR>
__global__ __launch_bounds__(256) void resize_kernel(const float* __restrict__ in,
                                                     float* __restrict__ out){
  int bidx = blockIdx.x;
  int ox = bidx % OUTD;
  int oy = (bidx / OUTD) % OUTD;
  int b  = bidx / (OUTD*OUTD);
  int c = threadIdx.x;

  float sy = (oy + 0.5f)*RR - 0.5f;
  float sx = (ox + 0.5f)*RR - 0.5f;
  int jy0 = (int)floorf(sy) - RR + 1;
  int jx0 = (int)floorf(sx) - RR + 1;

  float wy[2*RR], wx[2*RR];
  int   jys[2*RR], jxs[2*RR];
  int cy=0, cx=0; float sumy=0.f, sumx=0.f;
  #pragma unroll
  for(int t=0;t<2*RR;t++){
    int j = jy0 + t;
    if(j>=0 && j<HH){
      float w = 1.0f - fabsf((float)j - sy)/(float)RR;
      if(w > 0.f){ jys[cy]=j; wy[cy]=w; sumy+=w; cy++; }
    }
  }
  #pragma unroll
  for(int t=0;t<2*RR;t++){
    int j = jx0 + t;
    if(j>=0 && j<WWI){
      float w = 1.0f - fabsf((float)j - sx)/(float)RR;
      if(w > 0.f){ jxs[cx]=j; wx[cx]=w; sumx+=w; cx++; }
    }
  }
  float acc = 0.f;
  for(int i=0;i<cy;i++)
    for(int j=0;j<cx;j++)
      acc += wy[i]*wx[j]*in[(((size_t)b*HH + jys[i])*WWI + jxs[j])*CC + c];
  acc /= (sumy*sumx);
  out[(((size_t)b*OUTD + oy)*OUTD + ox)*CC + c] = acc;
}

// ------------- posenc + pyramid sampling -> X rows [chunk][XP] bf16, vectorized -------------
__global__ __launch_bounds__(256) void sample_encode_v2(
    const float* __restrict__ fg, const float* __restrict__ pyr1,
    const float* __restrict__ pyr2, const float* __restrict__ coords,
    u16* __restrict__ X, int m0, int mcount){
  int mi = blockIdx.x*2 + (threadIdx.x >> 7);
  if(mi >= mcount) return;
  int u = threadIdx.x & 127;
  int m = m0 + mi;
  int b = m / NN;
  int n = m % NN;
  float c0 = coords[(size_t)n*2 + 0];
  float c1 = coords[(size_t)n*2 + 1];
  u16* xrow = X + (size_t)mi*XP;

  if(u >= 64){
    if(u < 106){
      int p = u - 64;
      float v;
      if(p < 2){ v = (p==0) ? c0 : c1; }
      else {
        int k = (p-2) >> 2;
        int r = (p-2) & 3;
        float f = (float)(1u<<k) * 3.14159265358979323846f;
        float a = (r & 1) ? c1 : c0;
        v = (r < 2) ? sinf(a*f) : cosf(a*f);
      }
      xrow[p] = f2bf(v);
    } else {
      xrow[INDIM + (u - 106)] = 0;       // pad 810..831 (22 cols)
    }
    return;
  }

  int c4 = u*4;
  const float* grids[3];
  grids[0] = fg   + (size_t)b*HH*WWI*CC;
  grids[1] = pyr1 + (size_t)b*32*32*CC;
  grids[2] = pyr2 + (size_t)b*16*16*CC;
  const int dims[3] = {64, 32, 16};

  #pragma unroll
  for(int lvl=0; lvl<3; lvl++){
    int d = dims[lvl];
    float yy = (c0 + 1.0f)*0.5f*(float)(d-1);
    float xx = (c1 + 1.0f)*0.5f*(float)(d-1);
    yy = fminf(fmaxf(yy, 0.0f), (float)(d-1));
    xx = fminf(fmaxf(xx, 0.0f), (float)(d-1));
    int y0 = (int)yy, x0 = (int)xx;
    int y1 = min(y0+1, d-1), x1 = min(x0+1, d-1);
    float ty = yy - (float)y0, tx = xx - (float)x0;
    const float* g = grids[lvl];
    float4 v00 = *(const float4*)&g[((size_t)y0*d + x0)*CC + c4];
    float4 v01 = *(const float4*)&g[((size_t)y0*d + x1)*CC + c4];
    float4 v10 = *(const float4*)&g[((size_t)y1*d + x0)*CC + c4];
    float4 v11 = *(const float4*)&g[((size_t)y1*d + x1)*CC + c4];
    float w00 = (1.f-ty)*(1.f-tx), w01 = (1.f-ty)*tx, w10 = ty*(1.f-tx), w11 = ty*tx;
    float r0 = w00*v00.x + w01*v01.x + w10*v10.x + w11*v11.x;
    float r1 = w00*v00.y + w01*v01.y + w10*v10.y + w11*v11.y;
    float r2 = w00*v00.z + w01*v01.z + w10*v10.z + w11*v11.z;
    float r3 = w00*v00.w + w01*v01.w + w10*v10.w + w11*v11.w;
    unsigned lo = (unsigned)f2bf(r0) | ((unsigned)f2bf(r1) << 16);
    unsigned hi = (unsigned)f2bf(r2) | ((unsigned)f2bf(r3) << 16);
    unsigned* dst = (unsigned*)&xrow[42 + lvl*CC + c4];
    dst[0] = lo; dst[1] = hi;
  }
}

// ---------------- weight convert: W[k][256] fp32 -> Wb[n][Kp] bf16 (B^T, zero-padded) ------
__global__ __launch_bounds__(256) void wconv(const float* __restrict__ W,
                                             u16* __restrict__ Wb, int K, int Kp){
  int idx = blockIdx.x*256 + threadIdx.x;
  if(idx >= 256*Kp) return;
  int n = idx / Kp, k = idx % Kp;
  float v = (k < K) ? W[(size_t)k*MLPW + n] : 0.f;
  Wb[idx] = f2bf(v);
}

// wo [256][3] fp32 -> wob[16][256] bf16 (B^T, rows 3..15 zero)
__global__ __launch_bounds__(256) void wconv_out(const float* __restrict__ wo,
                                                 u16* __restrict__ wob){
  int idx = blockIdx.x*256 + threadIdx.x;
  if(idx >= 16*256) return;
  int n = idx >> 8, k = idx & 255;
  float v = (n < 3) ? wo[(size_t)k*3 + n] : 0.f;
  wob[idx] = f2bf(v);
}

// ------- fused MLP: 2-phase global_load_lds pipeline; H resident in LDS -------
// LDS pool (u16 units): Hs[128*260]=33280 | A0@33280 A1@37376 (4096 each) |
//                       B0@41472 B1@49664 (8192 each) | total 57856 u16 = 115712 B
__global__ __launch_bounds__(512, 2) void fused_mlp(
    const u16* __restrict__ X,
    const u16* __restrict__ wb0, const u16* __restrict__ wb1,
    const u16* __restrict__ wb2, const u16* __restrict__ wb3,
    const u16* __restrict__ wob,
    const float* __restrict__ b0, const float* __restrict__ b1,
    const float* __restrict__ b2, const float* __restrict__ b3,
    const float* __restrict__ bo,
    float* __restrict__ out, int m0){
  __shared__ u16 pool[57856];
  __shared__ float Os[FBM*4];
  u16* Hs = pool;
  u16* A0 = pool + 33280; u16* A1 = pool + 37376;
  u16* B0 = pool + 41472; u16* B1 = pool + 49664;

  int tid  = threadIdx.x;
  int lane = tid & 63, wv = tid >> 6;
  int wr = (wv>>2)*64, wc = (wv&3)*64;
  int rl = lane & 15;
  int koffe = (lane >> 4)*8;          // k-slice offset within a 32-K fragment (u16)
  int rg = (lane >> 4)*4;             // C/D row group

  size_t gm = (size_t)blockIdx.x*FBM;

  f32x4 acc[4][4];
  #pragma unroll
  for(int i=0;i<4;i++)
    #pragma unroll
    for(int j=0;j<4;j++) acc[i][j] = (f32x4){0.f,0.f,0.f,0.f};

  // staging geometry: thread t covers tile row t>>2, 16B piece (t&3)
  int arow = tid >> 2, acol = (tid & 3)*8;
  const u16* xsrc = X + (gm + arow)*XP + acol;
  u16* wdst = pool + wv*512;          // wave-uniform lane*16B region offset (u16: wv*512)

  auto stageA = [&](u16* buf, int xk){
    gl16(xsrc + xk, buf + wv*512);
  };
  auto stageB = [&](u16* buf, const u16* wb, int KpW, int gk){
    gl16(wb + (size_t)arow*KpW + gk + acol,        buf + wv*512);
    gl16(wb + (size_t)(128+arow)*KpW + gk + acol,  buf + 4096 + wv*512);
  };
  auto rdA = [&](const u16* buf, short8 af[4]){
    #pragma unroll
    for(int f=0;f<4;f++) af[f] = *(const short8*)&buf[(wr + f*16 + rl)*32 + koffe];
  };
  auto rdB = [&](const u16* buf, short8 bf[4]){
    #pragma unroll
    for(int f=0;f<4;f++) bf[f] = *(const short8*)&buf[(wc + f*16 + rl)*32 + koffe];
  };
  auto rdH = [&](int hk, short8 af[4]){
    #pragma unroll
    for(int f=0;f<4;f++) af[f] = *(const short8*)&Hs[(wr + f*16 + rl)*HSTR + hk + koffe];
  };
  auto domfma = [&](short8 af[4], short8 bf[4]){
    #pragma unroll
    for(int i=0;i<4;i++)
      #pragma unroll
      for(int j=0;j<4;j++)
        acc[i][j] = __builtin_amdgcn_mfma_f32_16x16x32_bf16(af[i], bf[j], acc[i][j], 0,0,0);
  };
  auto epilogue = [&](const float* __restrict__ bias){
    __syncthreads();
    #pragma unroll
    for(int j=0;j<4;j++){
      int ncol = wc + j*16 + rl;
      float bv = bias[ncol];
      #pragma unroll
      for(int i=0;i<4;i++)
        #pragma unroll
        for(int r=0;r<4;r++){
          int row = wr + i*16 + rg + r;
          Hs[row*HSTR + ncol] = f2bf(gelu_fast(acc[i][j][r] + bv));
        }
    }
    __syncthreads();
    #pragma unroll
    for(int i=0;i<4;i++)
      #pragma unroll
      for(int j=0;j<4;j++) acc[i][j] = (f32x4){0.f,0.f,0.f,0.f};
  };

  // X-staged layer: 26 K-steps, 2-phase double-buffered (A and B via global_load_lds)
  auto xlayer = [&](const u16* wb, int KpW, int gbase){
    stageA(A0, 0); stageB(B0, wb, KpW, gbase);
    __syncthreads();
    #pragma unroll 1
    for(int kc=0; kc<26; kc+=2){
      stageA(A1, (kc+1)*32); stageB(B1, wb, KpW, gbase+(kc+1)*32);
      { short8 af[4], bf[4]; rdA(A0,af); rdB(B0,bf); domfma(af,bf); }
      __syncthreads();                       // drains vmcnt: A1/B1 landed; A0/B0 reads done
      if(kc+2 < 26){ stageA(A0, (kc+2)*32); stageB(B0, wb, KpW, gbase+(kc+2)*32); }
      { short8 af[4], bf[4]; rdA(A1,af); rdB(B1,bf); domfma(af,bf); }
      __syncthreads();
    }
  };
  // H-resident layer: 8 K-steps, B staged 2-phase, A from Hs
  auto hlayer = [&](const u16* wb, int KpW, int gbase){
    stageB(B0, wb, KpW, gbase);
    __syncthreads();
    #pragma unroll 1
    for(int kc=0; kc<8; kc+=2){
      stageB(B1, wb, KpW, gbase+(kc+1)*32);
      { short8 af[4], bf[4]; rdH(kc*32, af); rdB(B0,bf); domfma(af,bf); }
      __syncthreads();
      if(kc+2 < 8) stageB(B0, wb, KpW, gbase+(kc+2)*32);
      { short8 af[4], bf[4]; rdH((kc+1)*32, af); rdB(B1,bf); domfma(af,bf); }
      __syncthreads();
    }
  };

  xlayer(wb0, XP, 0);          epilogue(b0);   // layer 0: X(832) @ w0
  hlayer(wb1, 256, 0);         epilogue(b1);   // layer 1
  hlayer(wb2, 256, 0);         epilogue(b2);   // layer 2
  hlayer(wb3, K3P, 0);                         // layer 3: H part (k 0..255)
  xlayer(wb3, K3P, 256);       epilogue(b3);   //          X part (k 256..1087)

  // ---- output layer via MFMA (waves 0,1), coalesced store via Os ----
  if(wv < 2){
    f32x4 oa[4];
    #pragma unroll
    for(int i=0;i<4;i++) oa[i] = (f32x4){0.f,0.f,0.f,0.f};
    #pragma unroll
    for(int c=0;c<8;c++){
      short8 af[4];
      #pragma unroll
      for(int f=0; f<4; f++)
        af[f] = *(const short8*)&Hs[(wv*64 + f*16 + rl)*HSTR + c*32 + koffe];
      short8 bf1 = *(const short8*)&wob[(size_t)rl*256 + c*32 + koffe];
      #pragma unroll
      for(int i=0;i<4;i++)
        oa[i] = __builtin_amdgcn_mfma_f32_16x16x32_bf16(af[i], bf1, oa[i], 0,0,0);
    }
    if(rl < 3){
      #pragma unroll
      for(int i=0;i<4;i++)
        #pragma unroll
        for(int r=0;r<4;r++)
          Os[(wv*64 + i*16 + rg + r)*4 + rl] = oa[i][r];
    }
  }
  __syncthreads();
  if(tid < FBM*3){
    float v = Os[(tid/3)*4 + (tid%3)];
    out[((size_t)m0 + gm)*3 + tid] = tanhf(v + bo[tid%3]);
  }
}

extern "C" void kernel_launch(void* const* d_in, const int* in_sizes, int n_in,
                              void* d_out, int out_size, void* d_ws, size_t ws_size,
                              hipStream_t stream){
  const float* fg     = (const float*)d_in[0];
  const float* coords = (const float*)d_in[1];
  const float* w0 = (const float*)d_in[2];  const float* b0 = (const float*)d_in[3];
  const float* w1 = (const float*)d_in[4];  const float* b1 = (const float*)d_in[5];
  const float* w2 = (const float*)d_in[6];  const float* b2 = (const float*)d_in[7];
  const float* w3 = (const float*)d_in[8];  const float* b3 = (const float*)d_in[9];
  const float* wo = (const float*)d_in[10]; const float* bo = (const float*)d_in[11];
  float* out = (float*)d_out;

  char* ws = (char*)d_ws;
  size_t off = 0;
  auto alloc = [&](size_t bytes)->void*{
    void* p = ws + off;
    off += (bytes + 255) & ~(size_t)255;
    return p;
  };
  auto rnd = [](size_t bytes)->size_t{ return (bytes + 255) & ~(size_t)255; };

  size_t fixed =
      rnd((size_t)BFULL*32*32*CC*4) + rnd((size_t)BFULL*16*16*CC*4) +
      rnd((size_t)256*XP*2) + rnd((size_t)256*256*2) +
      rnd((size_t)256*256*2) + rnd((size_t)256*K3P*2) + rnd((size_t)16*256*2);

  const size_t Mtot = (size_t)BFULL*NN; // 131072
  size_t chunk = Mtot;
  while(chunk > 128){
    size_t need = fixed + rnd(chunk*(size_t)XP*2);
    if(need <= ws_size) break;
    chunk >>= 1;
  }
  size_t min_need = fixed + rnd(chunk*(size_t)XP*2);
  if(min_need > ws_size || (chunk % 128) != 0) return;

  float* pyr1 = (float*)alloc((size_t)BFULL*32*32*CC*4);
  float* pyr2 = (float*)alloc((size_t)BFULL*16*16*CC*4);
  u16* wb0 = (u16*)alloc((size_t)256*XP*2);
  u16* wb1 = (u16*)alloc((size_t)256*256*2);
  u16* wb2 = (u16*)alloc((size_t)256*256*2);
  u16* wb3 = (u16*)alloc((size_t)256*K3P*2);
  u16* wob = (u16*)alloc((size_t)16*256*2);
  u16* X  = (u16*)alloc(chunk*(size_t)XP*2);

  resize_kernel<32,2><<<dim3(BFULL*32*32), dim3(256), 0, stream>>>(fg, pyr1);
  resize_kernel<16,4><<<dim3(BFULL*16*16), dim3(256), 0, stream>>>(fg, pyr2);
  wconv<<<dim3((256*XP +255)/256), dim3(256), 0, stream>>>(w0, wb0, INDIM, XP);
  wconv<<<dim3((256*256 +255)/256), dim3(256), 0, stream>>>(w1, wb1, 256, 256);
  wconv<<<dim3((256*256 +255)/256), dim3(256), 0, stream>>>(w2, wb2, 256, 256);
  wconv<<<dim3((256*K3P +255)/256), dim3(256), 0, stream>>>(w3, wb3, MLPW+INDIM, K3P);
  wconv_out<<<dim3(16), dim3(256), 0, stream>>>(wo, wob);

  for(size_t m0=0; m0<Mtot; m0+=chunk){
    int mc = (int)chunk;
    sample_encode_v2<<<dim3(mc/2), dim3(256), 0, stream>>>(fg, pyr1, pyr2, coords, X, (int)m0, mc);
    fused_mlp<<<dim3(mc/FBM), dim3(512), 0, stream>>>(X, wb0, wb1, wb2, wb3, wob,
                                                      b0, b1, b2, b3, bo,
                                                      out, (int)m0);
  }
}